// Round 19
// baseline (192.514 us; speedup 1.0000x reference)
//
#include <hip/hip_runtime.h>
#include <hip/hip_bf16.h>

typedef unsigned short u16;
typedef unsigned int   u32;
typedef __attribute__((ext_vector_type(8))) short bf16x8;
typedef __attribute__((ext_vector_type(4))) float f32x4;

// ---------- bf16 helpers ----------
__device__ __forceinline__ float bf2f(u16 u) {
    union { u32 i; float f; } x; x.i = ((u32)u) << 16; return x.f;
}
__device__ __forceinline__ u16 f2bf(float f) {
    union { float f; u32 i; } x; x.f = f;
    u32 i = x.i;
    u32 r = (i + 0x7fffu + ((i >> 16) & 1u)) >> 16;  // RNE
    return (u16)r;
}

// ---------- async global->LDS 16B DMA (linear dest, per-lane source) --------
__device__ __forceinline__ void gload16(const void* g, void* l) {
    __builtin_amdgcn_global_load_lds(
        (const __attribute__((address_space(1))) void*)g,
        (__attribute__((address_space(3))) void*)l, 16, 0, 0);
}

// =============== 1. merged setup: cos/sin table + weight transposes =========
__global__ __launch_bounds__(256) void k_init(
    float2* __restrict__ csT,
    const float* __restrict__ Wq, const float* __restrict__ Wk,
    const float* __restrict__ Wv, const float* __restrict__ Wo,
    u16* __restrict__ WTq, u16* __restrict__ WTk,
    u16* __restrict__ WTv, u16* __restrict__ WoT)
{
    const int bid = blockIdx.x;
    if (bid < 512) {
        int id = bid * 256 + threadIdx.x;   // 0..131071 = t*32+i
        int t = id >> 5, i = id & 31;
        double ang = pow(10000.0, -(double)i / 31.0);
        double a = (double)t * ang;
        csT[id] = make_float2((float)cos(a), (float)sin(a));
        return;
    }
    __shared__ float T[32][33];
    const int fid = bid - 512;              // 0..255
    const int bx = fid & 7, by = (fid >> 3) & 7, z = fid >> 6;
    const float* W = (z == 0) ? Wq : (z == 1) ? Wk : (z == 2) ? Wv : Wo;
    u16* WT        = (z == 0) ? WTq : (z == 1) ? WTk : (z == 2) ? WTv : WoT;
    int n0 = bx * 32, k0 = by * 32;
    int tx = threadIdx.x & 31, ty = threadIdx.x >> 5;   // ty 0..7
#pragma unroll
    for (int i = 0; i < 4; i++)
        T[ty * 4 + i][tx] = W[(k0 + ty * 4 + i) * 256 + n0 + tx];
    __syncthreads();
#pragma unroll
    for (int i = 0; i < 4; i++)
        WT[(n0 + ty * 4 + i) * 256 + k0 + tx] = f2bf(T[tx][ty * 4 + i]);
}

// =============== 2. fused QKV + W-axis attention (R18 best) =================
__global__ __launch_bounds__(512, 1) void k_qkv_fused(
    const float* __restrict__ x, const u16* __restrict__ WTall,
    const float* __restrict__ bq, const float* __restrict__ bk,
    const float* __restrict__ bv,
    const float2* __restrict__ csT,
    u16* __restrict__ qr, u16* __restrict__ kr, u16* __restrict__ vO,
    u16* __restrict__ v5)
{
    __shared__ alignas(16) char smem[163840];
    u16* Alds = (u16*)smem;                         // 64 KB (GEMM A)
    u16* BldsA[2] = { (u16*)(smem + 65536),         // 2 x 32 KB (GEMM B dbuf)
                      (u16*)(smem + 98304) };
    float2* SL = (float2*)(smem + 131072);          // 32 KB (cos,sin)

    const int tid = threadIdx.x;
    const int t0 = blockIdx.x * 128;
    const int lane = tid & 63, w = tid >> 6;

    const int srcChunk = (lane & 7) ^ (lane >> 3);
    const int rowInGrp = lane >> 3;

    // ---- in-kernel transpose: x (NCHW fp32) -> Alds [128 tok][256 c] bf16
    {
        float* Bf = (float*)(smem + 65536);         // 64 KB fp32 scratch
        const int b0 = t0 >> 12, sb0 = t0 & 4095;
        const float* xb = x + ((size_t)b0 * 256) * 4096 + sb0;
#pragma unroll
        for (int ch = 0; ch < 2; ++ch) {
#pragma unroll
            for (int p = 0; p < 8; ++p) {
                int it = p * 512 + tid;             // 0..4095
                int c = it >> 5, s4 = (it & 31) * 4;
                float4 v4 = *(const float4*)(xb + (size_t)(ch * 128 + c) * 4096 + s4);
                *(float4*)(Bf + c * 128 + s4) = v4;
            }
            __syncthreads();
#pragma unroll
            for (int p = 0; p < 4; ++p) {
                int it = p * 512 + tid;             // 0..2047
                int tok = it & 127, ck = it >> 7;   // ck 0..15
                u32 pk4[4];
#pragma unroll
                for (int jj = 0; jj < 4; ++jj) {
                    float lo = Bf[(ck * 8 + jj * 2)     * 128 + tok];
                    float hi = Bf[(ck * 8 + jj * 2 + 1) * 128 + tok];
                    asm("v_cvt_pk_bf16_f32 %0, %1, %2" : "=v"(pk4[jj]) : "v"(lo), "v"(hi));
                }
                int gc = ch * 16 + ck;              // global chunk 0..31
                int gcs = (gc & 24) | ((gc & 7) ^ (tok & 7));
                *(bf16x8*)(Alds + tok * 256 + gcs * 8) = *(bf16x8*)pk4;
            }
            __syncthreads();
        }
    }

    // ---- issue DMA for B slice 0 (overlapped by SL staging below)
#pragma unroll
    for (int q = 0; q < 4; ++q) {
        int rl = (w * 4 + q) * 8 + rowInGrp;        // row 0..255
        gload16(WTall + (size_t)rl * 256 + srcChunk * 8,
                BldsA[0] + (size_t)(w * 4 + q) * 512);
    }

    // ---- stage RoPE cos/sin slice for this block's 128 tokens
    {
        const int sb = t0 & 4095;
#pragma unroll
        for (int p = 0; p < 8; ++p) {
            int idx = p * 512 + tid;                // 0..4095
            SL[idx] = csT[(size_t)sb * 32 + idx];
        }
    }
    __syncthreads();                                // B slice 0 + SL ready

    const int wr = w >> 2, wc = w & 3;
    const int l15 = lane & 15, l4 = lane >> 4, l7 = lane & 7;

    f32x4 acc[4][4];   // after the mat loop this holds V's accumulators

#pragma unroll
    for (int mat = 0; mat < 3; ++mat) {
#pragma unroll
        for (int mi = 0; mi < 4; ++mi)
#pragma unroll
            for (int ni = 0; ni < 4; ++ni) acc[mi][ni] = (f32x4)0.f;

#pragma unroll
        for (int ks = 0; ks < 4; ++ks) {
            const int s = mat * 4 + ks;
            u16* Bl = BldsA[s & 1];
            // issue DMA for slice s+1 (lands by the barrier below)
            if (s < 11) {
                const int s2 = s + 1;
                const int mat2 = s2 >> 2, ks2 = s2 & 3;
#pragma unroll
                for (int q = 0; q < 4; ++q) {
                    int rl = (w * 4 + q) * 8 + rowInGrp;
                    gload16(WTall + (size_t)mat2 * 65536 + (size_t)rl * 256 +
                                ks2 * 64 + srcChunk * 8,
                            BldsA[s2 & 1] + (size_t)(w * 4 + q) * 512);
                }
            }
            // compute: 2 kk phases x 16 MFMA
#pragma unroll
            for (int kk = 0; kk < 2; ++kk) {
                bf16x8 af[4], bfr[4];
#pragma unroll
                for (int mi = 0; mi < 4; ++mi) {
                    int r = wr * 64 + mi * 16 + l15;
                    af[mi] = *(const bf16x8*)(Alds + r * 256 + (ks * 8 + ((kk * 4 + l4) ^ l7)) * 8);
                }
#pragma unroll
                for (int ni = 0; ni < 4; ++ni) {
                    int r = wc * 64 + ni * 16 + l15;
                    bfr[ni] = *(const bf16x8*)(Bl + r * 64 + ((kk * 4 + l4) ^ l7) * 8);
                }
#pragma unroll
                for (int mi = 0; mi < 4; ++mi)
#pragma unroll
                    for (int ni = 0; ni < 4; ++ni)
                        acc[mi][ni] = __builtin_amdgcn_mfma_f32_16x16x32_bf16(
                            af[mi], bfr[ni], acc[mi][ni], 0, 0, 0);
            }
            __syncthreads();       // drains DMA(s+1) + readers of Bl done
        }

        // ---- epilogue: bias (+ kscale + RoPE from SL), cvt_pk paired store
        const float* bias = (mat == 0) ? bq : (mat == 1) ? bk : bv;
        u16* out          = (mat == 0) ? qr : (mat == 1) ? kr : vO;
        const float kscale = (mat == 1) ? 0.125f : 1.0f;
        float bcol[4]; int ip[4];
#pragma unroll
        for (int ni = 0; ni < 4; ++ni) {
            bcol[ni] = bias[wc * 64 + ni * 16 + l15];
            ip[ni] = (ni * 16 + l15) >> 1;
        }
#pragma unroll
        for (int mi = 0; mi < 4; ++mi) {
#pragma unroll
            for (int rg = 0; rg < 4; ++rg) {
                const int sl = wr * 64 + mi * 16 + l4 * 4 + rg;   // local token
                size_t trow = (size_t)(t0 + sl) * 256;
#pragma unroll
                for (int ni = 0; ni < 4; ++ni) {
                    float val = (acc[mi][ni][rg] + bcol[ni]) * kscale;
                    float prt = __shfl_xor(val, 1);
                    float res, res2;
                    if (mat != 2) {
                        float2 cs = SL[sl * 32 + ip[ni]];
                        res  = fmaf(val, cs.x, -prt * cs.y);   // even out
                        res2 = fmaf(prt, cs.x,  val * cs.y);   // odd out
                    } else {
                        res = val; res2 = prt;
                    }
                    if (!(lane & 1)) {
                        u32 pk;
                        asm("v_cvt_pk_bf16_f32 %0, %1, %2" : "=v"(pk) : "v"(res), "v"(res2));
                        int o = wc * 64 + ni * 16 + l15;
                        *(u32*)(out + trow + o) = pk;
                    }
                }
            }
        }
    }

    // ================= Phase C: fused axis-0 flash ==========================
    __syncthreads();    // all waves done with Alds/Blds/SL -> reuse as VT/PL
    u16* VTl = (u16*)smem + w * 4608;               // 9216 B/wave: V^T [d][tok]
    u16* PLl = (u16*)(smem + 73728) + w * 4608;     // 9216 B/wave: P / O tile

    // ---- stash V from acc into VT, swizzled (tok granule g ^= d>>3)
    {
        float bcv[4];
#pragma unroll
        for (int ni = 0; ni < 4; ++ni) bcv[ni] = bv[wc * 64 + ni * 16 + l15];
#pragma unroll
        for (int mi = 0; mi < 4; ++mi)
#pragma unroll
            for (int ni = 0; ni < 4; ++ni) {
                int d = ni * 16 + l15;
                int gs = (mi * 2 + (l4 >> 1)) ^ (d >> 3);
                float e0 = acc[mi][ni][0] + bcv[ni], e1 = acc[mi][ni][1] + bcv[ni];
                float e2 = acc[mi][ni][2] + bcv[ni], e3 = acc[mi][ni][3] + bcv[ni];
                u32 p0, p1;
                asm("v_cvt_pk_bf16_f32 %0, %1, %2" : "=v"(p0) : "v"(e0), "v"(e1));
                asm("v_cvt_pk_bf16_f32 %0, %1, %2" : "=v"(p1) : "v"(e2), "v"(e3));
                uint2 pp; pp.x = p0; pp.y = p1;
                *(uint2*)(VTl + d * 72 + gs * 8 + (l4 & 1) * 4) = pp;
            }
    }

    // ---- Q/K fragments: re-read own just-written tiles (L2-hot)
    asm volatile("s_waitcnt vmcnt(0)" ::: "memory");
    const size_t qkb = (size_t)(t0 + wr * 64) * 256 + wc * 64;
    bf16x8 ka[4][2], qb[4][2];
#pragma unroll
    for (int t = 0; t < 4; ++t)
#pragma unroll
        for (int ks = 0; ks < 2; ++ks) {
            ka[t][ks] = *(const bf16x8*)(kr + qkb + (size_t)(t * 16 + l15) * 256 + ks * 32 + l4 * 8);
            qb[t][ks] = *(const bf16x8*)(qr + qkb + (size_t)(t * 16 + l15) * 256 + ks * 32 + l4 * 8);
        }

    // ---- S^T = K·Q^T
    f32x4 sacc[4][4];   // [kt][qt]
#pragma unroll
    for (int kt = 0; kt < 4; ++kt)
#pragma unroll
        for (int qt = 0; qt < 4; ++qt) sacc[kt][qt] = (f32x4)0.f;
#pragma unroll
    for (int ks = 0; ks < 2; ++ks)
#pragma unroll
        for (int kt = 0; kt < 4; ++kt)
#pragma unroll
            for (int qt = 0; qt < 4; ++qt)
                sacc[kt][qt] = __builtin_amdgcn_mfma_f32_16x16x32_bf16(
                    ka[kt][ks], qb[qt][ks], sacc[kt][qt], 0, 0, 0);

    // ---- softmax over k (mask |q-k|*decay folded; n = wc)
    const float decay = logf(1.0f - exp2f(-(1.0f + 0.75f * (float)wc)));
#pragma unroll
    for (int qt = 0; qt < 4; ++qt) {
        const int qq = qt * 16 + l15;
        float lsum = 0.f;
#pragma unroll
        for (int kt = 0; kt < 4; ++kt) {
            const int kb = kt * 16 + l4 * 4;
#pragma unroll
            for (int rr = 0; rr < 4; ++rr) {
                float s = sacc[kt][qt][rr] + fabsf((float)(qq - kb - rr)) * decay;
                s = __expf(s);
                sacc[kt][qt][rr] = s;
                lsum += s;
            }
        }
        lsum += __shfl_xor(lsum, 16);
        lsum += __shfl_xor(lsum, 32);
        const float rinv = 1.0f / lsum;
#pragma unroll
        for (int kt = 0; kt < 4; ++kt) {
            float e0 = sacc[kt][qt][0] * rinv, e1 = sacc[kt][qt][1] * rinv;
            float e2 = sacc[kt][qt][2] * rinv, e3 = sacc[kt][qt][3] * rinv;
            u32 p0, p1;
            asm("v_cvt_pk_bf16_f32 %0, %1, %2" : "=v"(p0) : "v"(e0), "v"(e1));
            asm("v_cvt_pk_bf16_f32 %0, %1, %2" : "=v"(p1) : "v"(e2), "v"(e3));
            uint2 pp; pp.x = p0; pp.y = p1;
            *(uint2*)(PLl + (qt * 16 + l15) * 72 + kt * 16 + l4 * 4) = pp;
        }
    }

    // ---- PV: O = P·V
    __builtin_amdgcn_s_waitcnt(0xC07F);
    bf16x8 pa[4][2], vb[4][2];
#pragma unroll
    for (int qt = 0; qt < 4; ++qt)
#pragma unroll
        for (int ks = 0; ks < 2; ++ks)
            pa[qt][ks] = *(const bf16x8*)(PLl + (qt * 16 + l15) * 72 + ks * 32 + l4 * 8);
#pragma unroll
    for (int dt = 0; dt < 4; ++dt)
#pragma unroll
        for (int ks = 0; ks < 2; ++ks) {
            int d = dt * 16 + l15;
            int g = (ks * 4 + l4) ^ (d >> 3);
            vb[dt][ks] = *(const bf16x8*)(VTl + d * 72 + g * 8);
        }

    f32x4 oacc[4][4];   // [qt][dt]
#pragma unroll
    for (int qt = 0; qt < 4; ++qt)
#pragma unroll
        for (int dt = 0; dt < 4; ++dt) oacc[qt][dt] = (f32x4)0.f;
#pragma unroll
    for (int ks = 0; ks < 2; ++ks)
#pragma unroll
        for (int qt = 0; qt < 4; ++qt)
#pragma unroll
            for (int dt = 0; dt < 4; ++dt)
                oacc[qt][dt] = __builtin_amdgcn_mfma_f32_16x16x32_bf16(
                    pa[qt][ks], vb[dt][ks], oacc[qt][dt], 0, 0, 0);

    // ---- restage O through PLl so each lane stores one full row
#pragma unroll
    for (int qt = 0; qt < 4; ++qt)
#pragma unroll
        for (int dt = 0; dt < 4; ++dt)
#pragma unroll
            for (int rr = 0; rr < 4; ++rr)
                PLl[(qt * 16 + l4 * 4 + rr) * 72 + dt * 16 + l15] = f2bf(oacc[qt][dt][rr]);
    __builtin_amdgcn_s_waitcnt(0xC07F);

    const int b0 = t0 >> 12;
    const int line = ((t0 & 4095) >> 6) + wr;       // h index of this wave's line
    size_t orow = ((size_t)((b0 * 64 + lane) * 4 + wc)) * 4096 + line * 64;
#pragma unroll
    for (int c = 0; c < 8; ++c)
        *(bf16x8*)(v5 + orow + c * 8) = *(const bf16x8*)(PLl + lane * 72 + c * 8);
}

// =============== 3. LEPE: 5x5 depthwise conv, register row-caching ==========
__global__ __launch_bounds__(256) void k_lepe(
    const u16* __restrict__ v, const float* __restrict__ dwk,
    const float* __restrict__ dwb, u16* __restrict__ lepe)
{
    __shared__ u16 VhU[12 * 12 * 64];   // [pos][c] bf16 raw, 18 KB
    __shared__ float Kl[25][64];        // 6.4 KB
    const int b = blockIdx.z, cg = blockIdx.y * 64;
    const int ty0 = (blockIdx.x >> 3) * 8, tx0 = (blockIdx.x & 7) * 8;
    const int tid = threadIdx.x;

    for (int idx = tid; idx < 1600; idx += 256) {
        int tap = idx >> 6, c = idx & 63;
        Kl[tap][c] = dwk[tap * 256 + cg + c];
    }
#pragma unroll
    for (int p = 0; p < 9; ++p) {
        int idx = p * 256 + tid;            // 0..2303
        int ch = idx & 15, pos = idx >> 4;  // chunk 0..15, pos 0..143
        int py = pos / 12, px = pos - py * 12;
        int gy = ty0 + py - 2, gx = tx0 + px - 2;
        ushort4 val = make_ushort4(0, 0, 0, 0);
        if (gy >= 0 && gy < 64 && gx >= 0 && gx < 64)
            val = *(const ushort4*)(v + (size_t)(b * 4096 + gy * 64 + gx) * 256 + cg + ch * 4);
        *(ushort4*)(VhU + pos * 64 + ch * 4) = val;
    }
    __syncthreads();

    const int c = tid & 63, pg = tid >> 6;
    float kreg[25];
#pragma unroll
    for (int t = 0; t < 25; t++) kreg[t] = Kl[t][c];
    const float bias = dwb[cg + c];

    float acc[2][8];
#pragma unroll
    for (int t = 0; t < 2; ++t)
#pragma unroll
        for (int ox = 0; ox < 8; ++ox) acc[t][ox] = bias;

#pragma unroll
    for (int rr = 0; rr < 6; ++rr) {
        const int r = pg * 2 + rr;          // input halo row
        float rv[12];
#pragma unroll
        for (int px = 0; px < 12; ++px)
            rv[px] = bf2f(VhU[(r * 12 + px) * 64 + c]);
        if (rr <= 4) {
            const int dy = rr;
#pragma unroll
            for (int ox = 0; ox < 8; ++ox)
#pragma unroll
                for (int dx = 0; dx < 5; ++dx)
                    acc[0][ox] = fmaf(rv[ox + dx], kreg[dy * 5 + dx], acc[0][ox]);
        }
        if (rr >= 1) {
            const int dy = rr - 1;
#pragma unroll
            for (int ox = 0; ox < 8; ++ox)
#pragma unroll
                for (int dx = 0; dx < 5; ++dx)
                    acc[1][ox] = fmaf(rv[ox + dx], kreg[dy * 5 + dx], acc[1][ox]);
        }
    }

#pragma unroll
    for (int t = 0; t < 2; ++t) {
        const int oy = pg * 2 + t;
#pragma unroll
        for (int ox = 0; ox < 8; ++ox)
            lepe[(size_t)(b * 4096 + (ty0 + oy) * 64 + tx0 + ox) * 256 + cg + c] =
                f2bf(acc[t][ox]);
    }
}

// =============== 4. H-axis attention, per-wave MFMA flash (fuses +lepe) =====
__global__ __launch_bounds__(256) void k_attn_h(
    const u16* __restrict__ qr, const u16* __restrict__ kr,
    const u16* __restrict__ vsrc, const u16* __restrict__ lepeP,
    u16* __restrict__ outb)
{
    __shared__ u16 VT[4][64 * 72];   // V^T tile [d][k], pitch 72, swizzled
    __shared__ u16 PL[4][64 * 72];   // P tile [q][k], pitch 72; reused for O

    const int tid = threadIdx.x;
    const int w = tid >> 6, lane = tid & 63;
    const int l15 = lane & 15, l4 = lane >> 4;
    const int wid = blockIdx.x * 4 + w;
    const int b = wid >> 8, xy = (wid >> 2) & 63, n = wid & 3;

    const size_t qkbase = ((size_t)(b * 4096 + xy)) * 256 + n * 64;
    const int qkstride = 64 * 256;
    const size_t vbase = ((size_t)((b * 64 + xy) * 4 + n)) * 4096;
    const int vstride = 64;

    u16* VTl = &VT[w][0];
    u16* PLl = &PL[w][0];

    bf16x8 vld[8];
    const int vrow = lane >> 3, vchunk = lane & 7;
#pragma unroll
    for (int it = 0; it < 8; ++it)
        vld[it] = *(const bf16x8*)(vsrc + vbase + (size_t)(it * 8 + vrow) * vstride + vchunk * 8);

    bf16x8 ka[4][2], qb[4][2];
#pragma unroll
    for (int t = 0; t < 4; ++t)
#pragma unroll
        for (int ks = 0; ks < 2; ++ks) {
            ka[t][ks] = *(const bf16x8*)(kr + qkbase + (size_t)(t * 16 + l15) * qkstride + ks * 32 + l4 * 8);
            qb[t][ks] = *(const bf16x8*)(qr + qkbase + (size_t)(t * 16 + l15) * qkstride + ks * 32 + l4 * 8);
        }

    f32x4 sacc[4][4];   // [kt][qt]
#pragma unroll
    for (int kt = 0; kt < 4; ++kt)
#pragma unroll
        for (int qt = 0; qt < 4; ++qt) sacc[kt][qt] = (f32x4)0.f;
    __builtin_amdgcn_s_setprio(1);
#pragma unroll
    for (int ks = 0; ks < 2; ++ks)
#pragma unroll
        for (int kt = 0; kt < 4; ++kt)
#pragma unroll
            for (int qt = 0; qt < 4; ++qt)
                sacc[kt][qt] = __builtin_amdgcn_mfma_f32_16x16x32_bf16(
                    ka[kt][ks], qb[qt][ks], sacc[kt][qt], 0, 0, 0);
    __builtin_amdgcn_s_setprio(0);

#pragma unroll
    for (int it = 0; it < 8; ++it) {
        int gp = ((it ^ vchunk) << 3) + vrow;
#pragma unroll
        for (int j = 0; j < 8; ++j) {
            int d = vchunk * 8 + j;
            VTl[d * 72 + gp] = (u16)vld[it][j];
        }
    }

    const float decay = logf(1.0f - exp2f(-(1.0f + 0.75f * (float)n)));
#pragma unroll
    for (int qt = 0; qt < 4; ++qt) {
        const int qq = qt * 16 + l15;
        float lsum = 0.f;
#pragma unroll
        for (int kt = 0; kt < 4; ++kt) {
            const int kb = kt * 16 + l4 * 4;
#pragma unroll
            for (int rr = 0; rr < 4; ++rr) {
                float s = sacc[kt][qt][rr] + fabsf((float)(qq - kb - rr)) * decay;
                s = __expf(s);
                sacc[kt][qt][rr] = s;
                lsum += s;
            }
        }
        lsum += __shfl_xor(lsum, 16);
        lsum += __shfl_xor(lsum, 32);
        const float rinv = 1.0f / lsum;
#pragma unroll
        for (int kt = 0; kt < 4; ++kt) {
            float e0 = sacc[kt][qt][0] * rinv, e1 = sacc[kt][qt][1] * rinv;
            float e2 = sacc[kt][qt][2] * rinv, e3 = sacc[kt][qt][3] * rinv;
            u32 p0, p1;
            asm("v_cvt_pk_bf16_f32 %0, %1, %2" : "=v"(p0) : "v"(e0), "v"(e1));
            asm("v_cvt_pk_bf16_f32 %0, %1, %2" : "=v"(p1) : "v"(e2), "v"(e3));
            uint2 pp; pp.x = p0; pp.y = p1;
            *(uint2*)(PLl + (qt * 16 + l15) * 72 + kt * 16 + l4 * 4) = pp;
        }
    }

    __builtin_amdgcn_s_waitcnt(0xC07F);
    bf16x8 pa[4][2], vb[4][2];
#pragma unroll
    for (int qt = 0; qt < 4; ++qt)
#pragma unroll
        for (int ks = 0; ks < 2; ++ks)
            pa[qt][ks] = *(const bf16x8*)(PLl + (qt * 16 + l15) * 72 + ks * 32 + l4 * 8);
#pragma unroll
    for (int dt = 0; dt < 4; ++dt)
#pragma unroll
        for (int ks = 0; ks < 2; ++ks) {
            int d = dt * 16 + l15;
            int g = (ks * 4 + l4) ^ (d >> 3);
            vb[dt][ks] = *(const bf16x8*)(VTl + d * 72 + g * 8);
        }

    f32x4 oacc[4][4];   // [qt][dt]
#pragma unroll
    for (int qt = 0; qt < 4; ++qt)
#pragma unroll
        for (int dt = 0; dt < 4; ++dt) oacc[qt][dt] = (f32x4)0.f;
    __builtin_amdgcn_s_setprio(1);
#pragma unroll
    for (int ks = 0; ks < 2; ++ks)
#pragma unroll
        for (int qt = 0; qt < 4; ++qt)
#pragma unroll
            for (int dt = 0; dt < 4; ++dt)
                oacc[qt][dt] = __builtin_amdgcn_mfma_f32_16x16x32_bf16(
                    pa[qt][ks], vb[dt][ks], oacc[qt][dt], 0, 0, 0);
    __builtin_amdgcn_s_setprio(0);

#pragma unroll
    for (int qt = 0; qt < 4; ++qt)
#pragma unroll
        for (int dt = 0; dt < 4; ++dt)
#pragma unroll
            for (int rr = 0; rr < 4; ++rr)
                PLl[(qt * 16 + l4 * 4 + rr) * 72 + dt * 16 + l15] = f2bf(oacc[qt][dt][rr]);
    __builtin_amdgcn_s_waitcnt(0xC07F);

    size_t orow = ((size_t)(b * 4096 + lane * 64 + xy)) * 256 + n * 64;
#pragma unroll
    for (int c = 0; c < 8; ++c) {
        bf16x8 o8 = *(const bf16x8*)(PLl + lane * 72 + c * 8);
        bf16x8 lp = *(const bf16x8*)(lepeP + orow + c * 8);
        u16 hv[8];
#pragma unroll
        for (int j = 0; j < 8; ++j)
            hv[j] = f2bf(bf2f((u16)o8[j]) + bf2f((u16)lp[j]));
        *(bf16x8*)(outb + orow + c * 8) = *(bf16x8*)hv;
    }
}

// =============== 5. output projection: 64-o x 256-t tile, 2 blocks/CU =======
// R19: Alds 32 KB (WoT 64 rows) + Blds dbuf 2x16 KB (BK=32) = 64 KB ->
// 2 blocks/CU = 16 waves/CU (genuine occupancy doubling). Wave tile 32x64,
// acc[2][4]. B swizzle: slot' = l4 ^ ((r>>1)&3) (2-way = free); DMA source
// pre-swizzled to match. Grid 1024, XCD-chunked so the 4 o-tiles of a
// token panel share one XCD L2.
__global__ __launch_bounds__(512) void k_proj_fused(
    const u16* __restrict__ WoT, const u16* __restrict__ attnL,
    const float* __restrict__ bo, float* __restrict__ y)
{
    __shared__ alignas(16) u16 Alds[64 * 256];      // 32 KB
    __shared__ alignas(16) u16 Blds[2][256 * 32];   // 2 x 16 KB

    const int tid = threadIdx.x;
    const int bid = blockIdx.x;                   // 1024 blocks
    const int xcd = bid & 7, slot = bid >> 3;     // slot 0..127
    const int tt = xcd * 32 + (slot >> 2);        // token tile 0..255
    const int ot = slot & 3;                      // o-tile 0..3
    const int t0 = tt * 256;
    const int o0 = ot * 64;

    const int lane = tid & 63, w = tid >> 6;
    const int ar = tid >> 5, ac = tid & 31;       // A staging: 16 rows/pass

    // B DMA coords: per pass 128 rows x 4 slots; source chunk pre-swizzled
    const int brow = tid >> 2, bslot = tid & 3;
    const int bsrc = bslot ^ ((brow >> 1) & 3);

    // ---- issue DMA for B slice 0 (2 passes), then stage A via regs
#pragma unroll
    for (int p = 0; p < 2; ++p) {
        int r = p * 128 + brow;
        gload16(attnL + (size_t)(t0 + r) * 256 + bsrc * 8,
                &Blds[0][0] + (size_t)(p * 128 + brow) * 32 + bslot * 8);
    }
    {
        bf16x8 areg[4];
#pragma unroll
        for (int p = 0; p < 4; ++p)
            areg[p] = *(const bf16x8*)(WoT + (size_t)(o0 + p * 16 + ar) * 256 + ac * 8);
#pragma unroll
        for (int p = 0; p < 4; ++p) {
            int r = p * 16 + ar;
            *(bf16x8*)(Alds + r * 256 + (ac ^ (r & 7)) * 8) = areg[p];
        }
    }
    __syncthreads();                                // A + B[0] ready

    const int wr = w >> 2, wc = w & 3;              // wave: 32-o half x 64-t qtr
    const int l15 = lane & 15, l4 = lane >> 4;

    f32x4 acc[2][4];
#pragma unroll
    for (int mi = 0; mi < 2; ++mi)
#pragma unroll
        for (int ni = 0; ni < 4; ++ni) acc[mi][ni] = (f32x4)0.f;

#pragma unroll
    for (int ks = 0; ks < 8; ++ks) {                // BK=32, 8 steps
        u16* Bl = &Blds[ks & 1][0];
        if (ks < 7) {                               // issue DMA for next slice
#pragma unroll
            for (int p = 0; p < 2; ++p) {
                int r = p * 128 + brow;
                gload16(attnL + (size_t)(t0 + r) * 256 + (ks + 1) * 32 + bsrc * 8,
                        &Blds[(ks + 1) & 1][0] + (size_t)(p * 128 + brow) * 32 + bslot * 8);
            }
        }
        {
            bf16x8 af[2], bfr[4];
#pragma unroll
            for (int mi = 0; mi < 2; ++mi) {
                int r = wr * 32 + mi * 16 + l15;
                int gc = ks * 4 + l4;               // global k-chunk 0..31
                int gcs = (gc & 24) | ((gc & 7) ^ (r & 7));
                af[mi] = *(const bf16x8*)(Alds + r * 256 + gcs * 8);
            }
#pragma unroll
            for (int ni = 0; ni < 4; ++ni) {
                int r = wc * 64 + ni * 16 + l15;
                int sl2 = l4 ^ ((r >> 1) & 3);
                bfr[ni] = *(const bf16x8*)(Bl + r * 32 + sl2 * 8);
            }
#pragma unroll
            for (int mi = 0; mi < 2; ++mi)
#pragma unroll
                for (int ni = 0; ni < 4; ++ni)
                    acc[mi][ni] = __builtin_amdgcn_mfma_f32_16x16x32_bf16(
                        af[mi], bfr[ni], acc[mi][ni], 0, 0, 0);
        }
        __syncthreads();                            // drains DMA + readers
    }

    const int b = t0 >> 12, sb = t0 & 4095;
#pragma unroll
    for (int mi = 0; mi < 2; ++mi) {
#pragma unroll
        for (int rg = 0; rg < 4; ++rg) {
            int o = o0 + wr * 32 + mi * 16 + l4 * 4 + rg;
            float bb = bo[o];
            float* yrow = y + ((size_t)(b * 256 + o)) * 4096 + sb + wc * 64;
#pragma unroll
            for (int ni = 0; ni < 4; ++ni)
                yrow[ni * 16 + l15] = acc[mi][ni][rg] + bb;
        }
    }
}

// ============================ launcher ======================================
extern "C" void kernel_launch(void* const* d_in, const int* in_sizes, int n_in,
                              void* d_out, int out_size, void* d_ws, size_t ws_size,
                              hipStream_t stream)
{
    const float* x   = (const float*)d_in[0];
    const float* Wq  = (const float*)d_in[1];
    const float* bq  = (const float*)d_in[2];
    const float* Wk  = (const float*)d_in[3];
    const float* bk  = (const float*)d_in[4];
    const float* Wv  = (const float*)d_in[5];
    const float* bv  = (const float*)d_in[6];
    const float* dwk = (const float*)d_in[7];
    const float* dwb = (const float*)d_in[8];
    const float* Wo  = (const float*)d_in[9];
    const float* bo  = (const float*)d_in[10];
    float* y = (float*)d_out;

    char* ws = (char*)d_ws;
    const size_t MB = 1024 * 1024;
    float2* csT = (float2*)(ws);                     // 1 MB [4096][32] (cos,sin)
    u16* WTq = (u16*)(ws + 1 * MB);                  // 4 x 128 KB (contiguous)
    u16* WTk = WTq + 65536;
    u16* WTv = WTk + 65536;
    u16* WoT = WTv + 65536;
    u16* qr   = (u16*)(ws + 2 * MB);                 // 32 MB each
    u16* kr   = (u16*)(ws + 2 * MB + 32 * MB);
    u16* v    = (u16*)(ws + 2 * MB + 64 * MB);
    u16* lepe = (u16*)(ws + 2 * MB + 96 * MB);
    u16* v5   = (u16*)(ws + 2 * MB + 128 * MB);      // (b,w,n,h,d)
    u16* attn = v;                                    // reuse (attn + lepe)

    k_init<<<dim3(768), dim3(256), 0, stream>>>(
        csT, Wq, Wk, Wv, Wo, WTq, WTk, WTv, WoT);
    k_qkv_fused<<<dim3(512), dim3(512), 0, stream>>>(
        x, WTq, bq, bk, bv, csT, qr, kr, v, v5);
    k_lepe<<<dim3(64, 4, 16), dim3(256), 0, stream>>>(v, dwk, dwb, lepe);
    k_attn_h<<<dim3(1024), dim3(256), 0, stream>>>(qr, kr, v5, lepe, attn);
    k_proj_fused<<<dim3(1024), dim3(512), 0, stream>>>(WoT, attn, bo, y);
}

// Round 20
// 184.852 us; speedup vs baseline: 1.0414x; 1.0414x over previous
//
#include <hip/hip_runtime.h>
#include <hip/hip_bf16.h>

typedef unsigned short u16;
typedef unsigned int   u32;
typedef __attribute__((ext_vector_type(8))) short bf16x8;
typedef __attribute__((ext_vector_type(4))) float f32x4;

// ---------- bf16 helpers ----------
__device__ __forceinline__ float bf2f(u16 u) {
    union { u32 i; float f; } x; x.i = ((u32)u) << 16; return x.f;
}
__device__ __forceinline__ u16 f2bf(float f) {
    union { float f; u32 i; } x; x.f = f;
    u32 i = x.i;
    u32 r = (i + 0x7fffu + ((i >> 16) & 1u)) >> 16;  // RNE
    return (u16)r;
}

// ---------- async global->LDS 16B DMA (linear dest, per-lane source) --------
__device__ __forceinline__ void gload16(const void* g, void* l) {
    __builtin_amdgcn_global_load_lds(
        (const __attribute__((address_space(1))) void*)g,
        (__attribute__((address_space(3))) void*)l, 16, 0, 0);
}

// =============== 1. merged setup: cos/sin table + weight transposes =========
__global__ __launch_bounds__(256) void k_init(
    float2* __restrict__ csT,
    const float* __restrict__ Wq, const float* __restrict__ Wk,
    const float* __restrict__ Wv, const float* __restrict__ Wo,
    u16* __restrict__ WTq, u16* __restrict__ WTk,
    u16* __restrict__ WTv, u16* __restrict__ WoT)
{
    const int bid = blockIdx.x;
    if (bid < 512) {
        int id = bid * 256 + threadIdx.x;   // 0..131071 = t*32+i
        int t = id >> 5, i = id & 31;
        double ang = pow(10000.0, -(double)i / 31.0);
        double a = (double)t * ang;
        csT[id] = make_float2((float)cos(a), (float)sin(a));
        return;
    }
    __shared__ float T[32][33];
    const int fid = bid - 512;              // 0..255
    const int bx = fid & 7, by = (fid >> 3) & 7, z = fid >> 6;
    const float* W = (z == 0) ? Wq : (z == 1) ? Wk : (z == 2) ? Wv : Wo;
    u16* WT        = (z == 0) ? WTq : (z == 1) ? WTk : (z == 2) ? WTv : WoT;
    int n0 = bx * 32, k0 = by * 32;
    int tx = threadIdx.x & 31, ty = threadIdx.x >> 5;   // ty 0..7
#pragma unroll
    for (int i = 0; i < 4; i++)
        T[ty * 4 + i][tx] = W[(k0 + ty * 4 + i) * 256 + n0 + tx];
    __syncthreads();
#pragma unroll
    for (int i = 0; i < 4; i++)
        WT[(n0 + ty * 4 + i) * 256 + k0 + tx] = f2bf(T[tx][ty * 4 + i]);
}

// =============== 2. fused QKV + W-axis attention ============================
// grid 512 (2 W-lines each), block 512 (8 waves = 2 lines x 4 heads).
// R18 best: in-kernel transpose (cvt_pk), dbuf GEMM with global_load_lds
// DMA, LDS-staged RoPE tables, per-wave axis-0 flash from acc registers.
__global__ __launch_bounds__(512, 1) void k_qkv_fused(
    const float* __restrict__ x, const u16* __restrict__ WTall,
    const float* __restrict__ bq, const float* __restrict__ bk,
    const float* __restrict__ bv,
    const float2* __restrict__ csT,
    u16* __restrict__ qr, u16* __restrict__ kr, u16* __restrict__ vO,
    u16* __restrict__ v5)
{
    __shared__ alignas(16) char smem[163840];
    u16* Alds = (u16*)smem;                         // 64 KB (GEMM A)
    u16* BldsA[2] = { (u16*)(smem + 65536),         // 2 x 32 KB (GEMM B dbuf)
                      (u16*)(smem + 98304) };
    float2* SL = (float2*)(smem + 131072);          // 32 KB (cos,sin)

    const int tid = threadIdx.x;
    const int t0 = blockIdx.x * 128;
    const int lane = tid & 63, w = tid >> 6;

    const int srcChunk = (lane & 7) ^ (lane >> 3);
    const int rowInGrp = lane >> 3;

    // ---- in-kernel transpose: x (NCHW fp32) -> Alds [128 tok][256 c] bf16
    {
        float* Bf = (float*)(smem + 65536);         // 64 KB fp32 scratch
        const int b0 = t0 >> 12, sb0 = t0 & 4095;
        const float* xb = x + ((size_t)b0 * 256) * 4096 + sb0;
#pragma unroll
        for (int ch = 0; ch < 2; ++ch) {
#pragma unroll
            for (int p = 0; p < 8; ++p) {
                int it = p * 512 + tid;             // 0..4095
                int c = it >> 5, s4 = (it & 31) * 4;
                float4 v4 = *(const float4*)(xb + (size_t)(ch * 128 + c) * 4096 + s4);
                *(float4*)(Bf + c * 128 + s4) = v4;
            }
            __syncthreads();
#pragma unroll
            for (int p = 0; p < 4; ++p) {
                int it = p * 512 + tid;             // 0..2047
                int tok = it & 127, ck = it >> 7;   // ck 0..15
                u32 pk4[4];
#pragma unroll
                for (int jj = 0; jj < 4; ++jj) {
                    float lo = Bf[(ck * 8 + jj * 2)     * 128 + tok];
                    float hi = Bf[(ck * 8 + jj * 2 + 1) * 128 + tok];
                    asm("v_cvt_pk_bf16_f32 %0, %1, %2" : "=v"(pk4[jj]) : "v"(lo), "v"(hi));
                }
                int gc = ch * 16 + ck;              // global chunk 0..31
                int gcs = (gc & 24) | ((gc & 7) ^ (tok & 7));
                *(bf16x8*)(Alds + tok * 256 + gcs * 8) = *(bf16x8*)pk4;
            }
            __syncthreads();
        }
    }

    // ---- issue DMA for B slice 0 (overlapped by SL staging below)
#pragma unroll
    for (int q = 0; q < 4; ++q) {
        int rl = (w * 4 + q) * 8 + rowInGrp;        // row 0..255
        gload16(WTall + (size_t)rl * 256 + srcChunk * 8,
                BldsA[0] + (size_t)(w * 4 + q) * 512);
    }

    // ---- stage RoPE cos/sin slice for this block's 128 tokens
    {
        const int sb = t0 & 4095;
#pragma unroll
        for (int p = 0; p < 8; ++p) {
            int idx = p * 512 + tid;                // 0..4095
            SL[idx] = csT[(size_t)sb * 32 + idx];
        }
    }
    __syncthreads();                                // B slice 0 + SL ready

    const int wr = w >> 2, wc = w & 3;
    const int l15 = lane & 15, l4 = lane >> 4, l7 = lane & 7;

    f32x4 acc[4][4];   // after the mat loop this holds V's accumulators

#pragma unroll
    for (int mat = 0; mat < 3; ++mat) {
#pragma unroll
        for (int mi = 0; mi < 4; ++mi)
#pragma unroll
            for (int ni = 0; ni < 4; ++ni) acc[mi][ni] = (f32x4)0.f;

#pragma unroll
        for (int ks = 0; ks < 4; ++ks) {
            const int s = mat * 4 + ks;
            u16* Bl = BldsA[s & 1];
            // issue DMA for slice s+1 (lands by the barrier below)
            if (s < 11) {
                const int s2 = s + 1;
                const int mat2 = s2 >> 2, ks2 = s2 & 3;
#pragma unroll
                for (int q = 0; q < 4; ++q) {
                    int rl = (w * 4 + q) * 8 + rowInGrp;
                    gload16(WTall + (size_t)mat2 * 65536 + (size_t)rl * 256 +
                                ks2 * 64 + srcChunk * 8,
                            BldsA[s2 & 1] + (size_t)(w * 4 + q) * 512);
                }
            }
            // compute: 2 kk phases x 16 MFMA
#pragma unroll
            for (int kk = 0; kk < 2; ++kk) {
                bf16x8 af[4], bfr[4];
#pragma unroll
                for (int mi = 0; mi < 4; ++mi) {
                    int r = wr * 64 + mi * 16 + l15;
                    af[mi] = *(const bf16x8*)(Alds + r * 256 + (ks * 8 + ((kk * 4 + l4) ^ l7)) * 8);
                }
#pragma unroll
                for (int ni = 0; ni < 4; ++ni) {
                    int r = wc * 64 + ni * 16 + l15;
                    bfr[ni] = *(const bf16x8*)(Bl + r * 64 + ((kk * 4 + l4) ^ l7) * 8);
                }
#pragma unroll
                for (int mi = 0; mi < 4; ++mi)
#pragma unroll
                    for (int ni = 0; ni < 4; ++ni)
                        acc[mi][ni] = __builtin_amdgcn_mfma_f32_16x16x32_bf16(
                            af[mi], bfr[ni], acc[mi][ni], 0, 0, 0);
            }
            __syncthreads();       // drains DMA(s+1) + readers of Bl done
        }

        // ---- epilogue: bias (+ kscale + RoPE from SL), cvt_pk paired store
        const float* bias = (mat == 0) ? bq : (mat == 1) ? bk : bv;
        u16* out          = (mat == 0) ? qr : (mat == 1) ? kr : vO;
        const float kscale = (mat == 1) ? 0.125f : 1.0f;
        float bcol[4]; int ip[4];
#pragma unroll
        for (int ni = 0; ni < 4; ++ni) {
            bcol[ni] = bias[wc * 64 + ni * 16 + l15];
            ip[ni] = (ni * 16 + l15) >> 1;
        }
#pragma unroll
        for (int mi = 0; mi < 4; ++mi) {
#pragma unroll
            for (int rg = 0; rg < 4; ++rg) {
                const int sl = wr * 64 + mi * 16 + l4 * 4 + rg;   // local token
                size_t trow = (size_t)(t0 + sl) * 256;
#pragma unroll
                for (int ni = 0; ni < 4; ++ni) {
                    float val = (acc[mi][ni][rg] + bcol[ni]) * kscale;
                    float prt = __shfl_xor(val, 1);
                    float res, res2;
                    if (mat != 2) {
                        float2 cs = SL[sl * 32 + ip[ni]];
                        res  = fmaf(val, cs.x, -prt * cs.y);   // even out
                        res2 = fmaf(prt, cs.x,  val * cs.y);   // odd out
                    } else {
                        res = val; res2 = prt;
                    }
                    if (!(lane & 1)) {
                        u32 pk;
                        asm("v_cvt_pk_bf16_f32 %0, %1, %2" : "=v"(pk) : "v"(res), "v"(res2));
                        int o = wc * 64 + ni * 16 + l15;
                        *(u32*)(out + trow + o) = pk;
                    }
                }
            }
        }
    }

    // ================= Phase C: fused axis-0 flash ==========================
    __syncthreads();    // all waves done with Alds/Blds/SL -> reuse as VT/PL
    u16* VTl = (u16*)smem + w * 4608;               // 9216 B/wave: V^T [d][tok]
    u16* PLl = (u16*)(smem + 73728) + w * 4608;     // 9216 B/wave: P / O tile

    // ---- stash V from acc into VT, swizzled (tok granule g ^= d>>3)
    {
        float bcv[4];
#pragma unroll
        for (int ni = 0; ni < 4; ++ni) bcv[ni] = bv[wc * 64 + ni * 16 + l15];
#pragma unroll
        for (int mi = 0; mi < 4; ++mi)
#pragma unroll
            for (int ni = 0; ni < 4; ++ni) {
                int d = ni * 16 + l15;
                int gs = (mi * 2 + (l4 >> 1)) ^ (d >> 3);
                float e0 = acc[mi][ni][0] + bcv[ni], e1 = acc[mi][ni][1] + bcv[ni];
                float e2 = acc[mi][ni][2] + bcv[ni], e3 = acc[mi][ni][3] + bcv[ni];
                u32 p0, p1;
                asm("v_cvt_pk_bf16_f32 %0, %1, %2" : "=v"(p0) : "v"(e0), "v"(e1));
                asm("v_cvt_pk_bf16_f32 %0, %1, %2" : "=v"(p1) : "v"(e2), "v"(e3));
                uint2 pp; pp.x = p0; pp.y = p1;
                *(uint2*)(VTl + d * 72 + gs * 8 + (l4 & 1) * 4) = pp;
            }
    }

    // ---- Q/K fragments: re-read own just-written tiles (L2-hot)
    asm volatile("s_waitcnt vmcnt(0)" ::: "memory");
    const size_t qkb = (size_t)(t0 + wr * 64) * 256 + wc * 64;
    bf16x8 ka[4][2], qb[4][2];
#pragma unroll
    for (int t = 0; t < 4; ++t)
#pragma unroll
        for (int ks = 0; ks < 2; ++ks) {
            ka[t][ks] = *(const bf16x8*)(kr + qkb + (size_t)(t * 16 + l15) * 256 + ks * 32 + l4 * 8);
            qb[t][ks] = *(const bf16x8*)(qr + qkb + (size_t)(t * 16 + l15) * 256 + ks * 32 + l4 * 8);
        }

    // ---- S^T = K·Q^T
    f32x4 sacc[4][4];   // [kt][qt]
#pragma unroll
    for (int kt = 0; kt < 4; ++kt)
#pragma unroll
        for (int qt = 0; qt < 4; ++qt) sacc[kt][qt] = (f32x4)0.f;
#pragma unroll
    for (int ks = 0; ks < 2; ++ks)
#pragma unroll
        for (int kt = 0; kt < 4; ++kt)
#pragma unroll
            for (int qt = 0; qt < 4; ++qt)
                sacc[kt][qt] = __builtin_amdgcn_mfma_f32_16x16x32_bf16(
                    ka[kt][ks], qb[qt][ks], sacc[kt][qt], 0, 0, 0);

    // ---- softmax over k (mask |q-k|*decay folded; n = wc)
    const float decay = logf(1.0f - exp2f(-(1.0f + 0.75f * (float)wc)));
#pragma unroll
    for (int qt = 0; qt < 4; ++qt) {
        const int qq = qt * 16 + l15;
        float lsum = 0.f;
#pragma unroll
        for (int kt = 0; kt < 4; ++kt) {
            const int kb = kt * 16 + l4 * 4;
#pragma unroll
            for (int rr = 0; rr < 4; ++rr) {
                float s = sacc[kt][qt][rr] + fabsf((float)(qq - kb - rr)) * decay;
                s = __expf(s);
                sacc[kt][qt][rr] = s;
                lsum += s;
            }
        }
        lsum += __shfl_xor(lsum, 16);
        lsum += __shfl_xor(lsum, 32);
        const float rinv = 1.0f / lsum;
#pragma unroll
        for (int kt = 0; kt < 4; ++kt) {
            float e0 = sacc[kt][qt][0] * rinv, e1 = sacc[kt][qt][1] * rinv;
            float e2 = sacc[kt][qt][2] * rinv, e3 = sacc[kt][qt][3] * rinv;
            u32 p0, p1;
            asm("v_cvt_pk_bf16_f32 %0, %1, %2" : "=v"(p0) : "v"(e0), "v"(e1));
            asm("v_cvt_pk_bf16_f32 %0, %1, %2" : "=v"(p1) : "v"(e2), "v"(e3));
            uint2 pp; pp.x = p0; pp.y = p1;
            *(uint2*)(PLl + (qt * 16 + l15) * 72 + kt * 16 + l4 * 4) = pp;
        }
    }

    // ---- PV: O = P·V
    __builtin_amdgcn_s_waitcnt(0xC07F);
    bf16x8 pa[4][2], vb[4][2];
#pragma unroll
    for (int qt = 0; qt < 4; ++qt)
#pragma unroll
        for (int ks = 0; ks < 2; ++ks)
            pa[qt][ks] = *(const bf16x8*)(PLl + (qt * 16 + l15) * 72 + ks * 32 + l4 * 8);
#pragma unroll
    for (int dt = 0; dt < 4; ++dt)
#pragma unroll
        for (int ks = 0; ks < 2; ++ks) {
            int d = dt * 16 + l15;
            int g = (ks * 4 + l4) ^ (d >> 3);
            vb[dt][ks] = *(const bf16x8*)(VTl + d * 72 + g * 8);
        }

    f32x4 oacc[4][4];   // [qt][dt]
#pragma unroll
    for (int qt = 0; qt < 4; ++qt)
#pragma unroll
        for (int dt = 0; dt < 4; ++dt) oacc[qt][dt] = (f32x4)0.f;
#pragma unroll
    for (int ks = 0; ks < 2; ++ks)
#pragma unroll
        for (int qt = 0; qt < 4; ++qt)
#pragma unroll
            for (int dt = 0; dt < 4; ++dt)
                oacc[qt][dt] = __builtin_amdgcn_mfma_f32_16x16x32_bf16(
                    pa[qt][ks], vb[dt][ks], oacc[qt][dt], 0, 0, 0);

    // ---- restage O through PLl so each lane stores one full row
#pragma unroll
    for (int qt = 0; qt < 4; ++qt)
#pragma unroll
        for (int dt = 0; dt < 4; ++dt)
#pragma unroll
            for (int rr = 0; rr < 4; ++rr)
                PLl[(qt * 16 + l4 * 4 + rr) * 72 + dt * 16 + l15] = f2bf(oacc[qt][dt][rr]);
    __builtin_amdgcn_s_waitcnt(0xC07F);

    const int b0 = t0 >> 12;
    const int line = ((t0 & 4095) >> 6) + wr;       // h index of this wave's line
    size_t orow = ((size_t)((b0 * 64 + lane) * 4 + wc)) * 4096 + line * 64;
#pragma unroll
    for (int c = 0; c < 8; ++c)
        *(bf16x8*)(v5 + orow + c * 8) = *(const bf16x8*)(PLl + lane * 72 + c * 8);
}

// =============== 3. LEPE: 5x5 depthwise conv, register row-caching ==========
__global__ __launch_bounds__(256) void k_lepe(
    const u16* __restrict__ v, const float* __restrict__ dwk,
    const float* __restrict__ dwb, u16* __restrict__ lepe)
{
    __shared__ u16 VhU[12 * 12 * 64];   // [pos][c] bf16 raw, 18 KB
    __shared__ float Kl[25][64];        // 6.4 KB
    const int b = blockIdx.z, cg = blockIdx.y * 64;
    const int ty0 = (blockIdx.x >> 3) * 8, tx0 = (blockIdx.x & 7) * 8;
    const int tid = threadIdx.x;

    for (int idx = tid; idx < 1600; idx += 256) {
        int tap = idx >> 6, c = idx & 63;
        Kl[tap][c] = dwk[tap * 256 + cg + c];
    }
#pragma unroll
    for (int p = 0; p < 9; ++p) {
        int idx = p * 256 + tid;            // 0..2303
        int ch = idx & 15, pos = idx >> 4;  // chunk 0..15, pos 0..143
        int py = pos / 12, px = pos - py * 12;
        int gy = ty0 + py - 2, gx = tx0 + px - 2;
        ushort4 val = make_ushort4(0, 0, 0, 0);
        if (gy >= 0 && gy < 64 && gx >= 0 && gx < 64)
            val = *(const ushort4*)(v + (size_t)(b * 4096 + gy * 64 + gx) * 256 + cg + ch * 4);
        *(ushort4*)(VhU + pos * 64 + ch * 4) = val;
    }
    __syncthreads();

    const int c = tid & 63, pg = tid >> 6;
    float kreg[25];
#pragma unroll
    for (int t = 0; t < 25; t++) kreg[t] = Kl[t][c];
    const float bias = dwb[cg + c];

    float acc[2][8];
#pragma unroll
    for (int t = 0; t < 2; ++t)
#pragma unroll
        for (int ox = 0; ox < 8; ++ox) acc[t][ox] = bias;

#pragma unroll
    for (int rr = 0; rr < 6; ++rr) {
        const int r = pg * 2 + rr;          // input halo row
        float rv[12];
#pragma unroll
        for (int px = 0; px < 12; ++px)
            rv[px] = bf2f(VhU[(r * 12 + px) * 64 + c]);
        if (rr <= 4) {
            const int dy = rr;
#pragma unroll
            for (int ox = 0; ox < 8; ++ox)
#pragma unroll
                for (int dx = 0; dx < 5; ++dx)
                    acc[0][ox] = fmaf(rv[ox + dx], kreg[dy * 5 + dx], acc[0][ox]);
        }
        if (rr >= 1) {
            const int dy = rr - 1;
#pragma unroll
            for (int ox = 0; ox < 8; ++ox)
#pragma unroll
                for (int dx = 0; dx < 5; ++dx)
                    acc[1][ox] = fmaf(rv[ox + dx], kreg[dy * 5 + dx], acc[1][ox]);
        }
    }

#pragma unroll
    for (int t = 0; t < 2; ++t) {
        const int oy = pg * 2 + t;
#pragma unroll
        for (int ox = 0; ox < 8; ++ox)
            lepe[(size_t)(b * 4096 + (ty0 + oy) * 64 + tx0 + ox) * 256 + cg + c] =
                f2bf(acc[t][ox]);
    }
}

// =============== 4. H-axis attention, per-wave MFMA flash (fuses +lepe) =====
__global__ __launch_bounds__(256) void k_attn_h(
    const u16* __restrict__ qr, const u16* __restrict__ kr,
    const u16* __restrict__ vsrc, const u16* __restrict__ lepeP,
    u16* __restrict__ outb)
{
    __shared__ u16 VT[4][64 * 72];   // V^T tile [d][k], pitch 72, swizzled
    __shared__ u16 PL[4][64 * 72];   // P tile [q][k], pitch 72; reused for O

    const int tid = threadIdx.x;
    const int w = tid >> 6, lane = tid & 63;
    const int l15 = lane & 15, l4 = lane >> 4;
    const int wid = blockIdx.x * 4 + w;
    const int b = wid >> 8, xy = (wid >> 2) & 63, n = wid & 3;

    const size_t qkbase = ((size_t)(b * 4096 + xy)) * 256 + n * 64;
    const int qkstride = 64 * 256;
    const size_t vbase = ((size_t)((b * 64 + xy) * 4 + n)) * 4096;
    const int vstride = 64;

    u16* VTl = &VT[w][0];
    u16* PLl = &PL[w][0];

    bf16x8 vld[8];
    const int vrow = lane >> 3, vchunk = lane & 7;
#pragma unroll
    for (int it = 0; it < 8; ++it)
        vld[it] = *(const bf16x8*)(vsrc + vbase + (size_t)(it * 8 + vrow) * vstride + vchunk * 8);

    bf16x8 ka[4][2], qb[4][2];
#pragma unroll
    for (int t = 0; t < 4; ++t)
#pragma unroll
        for (int ks = 0; ks < 2; ++ks) {
            ka[t][ks] = *(const bf16x8*)(kr + qkbase + (size_t)(t * 16 + l15) * qkstride + ks * 32 + l4 * 8);
            qb[t][ks] = *(const bf16x8*)(qr + qkbase + (size_t)(t * 16 + l15) * qkstride + ks * 32 + l4 * 8);
        }

    f32x4 sacc[4][4];   // [kt][qt]
#pragma unroll
    for (int kt = 0; kt < 4; ++kt)
#pragma unroll
        for (int qt = 0; qt < 4; ++qt) sacc[kt][qt] = (f32x4)0.f;
    __builtin_amdgcn_s_setprio(1);
#pragma unroll
    for (int ks = 0; ks < 2; ++ks)
#pragma unroll
        for (int kt = 0; kt < 4; ++kt)
#pragma unroll
            for (int qt = 0; qt < 4; ++qt)
                sacc[kt][qt] = __builtin_amdgcn_mfma_f32_16x16x32_bf16(
                    ka[kt][ks], qb[qt][ks], sacc[kt][qt], 0, 0, 0);
    __builtin_amdgcn_s_setprio(0);

#pragma unroll
    for (int it = 0; it < 8; ++it) {
        int gp = ((it ^ vchunk) << 3) + vrow;
#pragma unroll
        for (int j = 0; j < 8; ++j) {
            int d = vchunk * 8 + j;
            VTl[d * 72 + gp] = (u16)vld[it][j];
        }
    }

    const float decay = logf(1.0f - exp2f(-(1.0f + 0.75f * (float)n)));
#pragma unroll
    for (int qt = 0; qt < 4; ++qt) {
        const int qq = qt * 16 + l15;
        float lsum = 0.f;
#pragma unroll
        for (int kt = 0; kt < 4; ++kt) {
            const int kb = kt * 16 + l4 * 4;
#pragma unroll
            for (int rr = 0; rr < 4; ++rr) {
                float s = sacc[kt][qt][rr] + fabsf((float)(qq - kb - rr)) * decay;
                s = __expf(s);
                sacc[kt][qt][rr] = s;
                lsum += s;
            }
        }
        lsum += __shfl_xor(lsum, 16);
        lsum += __shfl_xor(lsum, 32);
        const float rinv = 1.0f / lsum;
#pragma unroll
        for (int kt = 0; kt < 4; ++kt) {
            float e0 = sacc[kt][qt][0] * rinv, e1 = sacc[kt][qt][1] * rinv;
            float e2 = sacc[kt][qt][2] * rinv, e3 = sacc[kt][qt][3] * rinv;
            u32 p0, p1;
            asm("v_cvt_pk_bf16_f32 %0, %1, %2" : "=v"(p0) : "v"(e0), "v"(e1));
            asm("v_cvt_pk_bf16_f32 %0, %1, %2" : "=v"(p1) : "v"(e2), "v"(e3));
            uint2 pp; pp.x = p0; pp.y = p1;
            *(uint2*)(PLl + (qt * 16 + l15) * 72 + kt * 16 + l4 * 4) = pp;
        }
    }

    __builtin_amdgcn_s_waitcnt(0xC07F);
    bf16x8 pa[4][2], vb[4][2];
#pragma unroll
    for (int qt = 0; qt < 4; ++qt)
#pragma unroll
        for (int ks = 0; ks < 2; ++ks)
            pa[qt][ks] = *(const bf16x8*)(PLl + (qt * 16 + l15) * 72 + ks * 32 + l4 * 8);
#pragma unroll
    for (int dt = 0; dt < 4; ++dt)
#pragma unroll
        for (int ks = 0; ks < 2; ++ks) {
            int d = dt * 16 + l15;
            int g = (ks * 4 + l4) ^ (d >> 3);
            vb[dt][ks] = *(const bf16x8*)(VTl + d * 72 + g * 8);
        }

    f32x4 oacc[4][4];   // [qt][dt]
#pragma unroll
    for (int qt = 0; qt < 4; ++qt)
#pragma unroll
        for (int dt = 0; dt < 4; ++dt) oacc[qt][dt] = (f32x4)0.f;
    __builtin_amdgcn_s_setprio(1);
#pragma unroll
    for (int ks = 0; ks < 2; ++ks)
#pragma unroll
        for (int qt = 0; qt < 4; ++qt)
#pragma unroll
            for (int dt = 0; dt < 4; ++dt)
                oacc[qt][dt] = __builtin_amdgcn_mfma_f32_16x16x32_bf16(
                    pa[qt][ks], vb[dt][ks], oacc[qt][dt], 0, 0, 0);
    __builtin_amdgcn_s_setprio(0);

#pragma unroll
    for (int qt = 0; qt < 4; ++qt)
#pragma unroll
        for (int dt = 0; dt < 4; ++dt)
#pragma unroll
            for (int rr = 0; rr < 4; ++rr)
                PLl[(qt * 16 + l4 * 4 + rr) * 72 + dt * 16 + l15] = f2bf(oacc[qt][dt][rr]);
    __builtin_amdgcn_s_waitcnt(0xC07F);

    size_t orow = ((size_t)(b * 4096 + lane * 64 + xy)) * 256 + n * 64;
#pragma unroll
    for (int c = 0; c < 8; ++c) {
        bf16x8 o8 = *(const bf16x8*)(PLl + lane * 72 + c * 8);
        bf16x8 lp = *(const bf16x8*)(lepeP + orow + c * 8);
        u16 hv[8];
#pragma unroll
        for (int j = 0; j < 8; ++j)
            hv[j] = f2bf(bf2f((u16)o8[j]) + bf2f((u16)lp[j]));
        *(bf16x8*)(outb + orow + c * 8) = *(bf16x8*)hv;
    }
}

// =============== 5. output projection: A resident, B via global_load_lds ====
__global__ __launch_bounds__(512, 1) void k_proj_fused(
    const u16* __restrict__ WoT, const u16* __restrict__ attnL,
    const float* __restrict__ bo, float* __restrict__ y)
{
    __shared__ alignas(16) u16 Alds[128 * 256];     // 64 KB
    __shared__ alignas(16) u16 Blds[2][256 * 64];   // 64 KB

    const int tid = threadIdx.x;
    const int bid = blockIdx.x;                   // 512 blocks
    const int xcd = bid & 7, slot = bid >> 3;
    const int tt = xcd * 32 + (slot >> 1);
    const int oh = slot & 1;
    const int t0 = tt * 256;
    const int o0 = oh * 128;

    const int lane = tid & 63, w = tid >> 6;
    const int srcChunk = (lane & 7) ^ (lane >> 3);
    const int rowInGrp = lane >> 3;
    const int ar = tid >> 5, ac = tid & 31;

    // ---- issue DMA for B slice 0, then stage A via regs
#pragma unroll
    for (int q = 0; q < 4; ++q) {
        int rl = (w * 4 + q) * 8 + rowInGrp;        // local row 0..255
        gload16(attnL + (size_t)(t0 + rl) * 256 + srcChunk * 8,
                &Blds[0][0] + (size_t)(w * 4 + q) * 512);
    }
    {
        bf16x8 areg[8];
#pragma unroll
        for (int p = 0; p < 8; ++p)
            areg[p] = *(const bf16x8*)(WoT + (size_t)(o0 + p * 16 + ar) * 256 + ac * 8);
#pragma unroll
        for (int p = 0; p < 8; ++p) {
            int r = p * 16 + ar;
            *(bf16x8*)(Alds + r * 256 + (ac ^ (r & 7)) * 8) = areg[p];
        }
    }
    __syncthreads();                                // A + B[0] ready

    const int wr = w >> 2, wc = w & 3;
    const int l15 = lane & 15, l4 = lane >> 4, l7 = lane & 7;

    f32x4 acc[4][4];
#pragma unroll
    for (int mi = 0; mi < 4; ++mi)
#pragma unroll
        for (int ni = 0; ni < 4; ++ni) acc[mi][ni] = (f32x4)0.f;

#pragma unroll
    for (int ks = 0; ks < 4; ++ks) {
        u16* Bl = &Blds[ks & 1][0];
        if (ks < 3) {                               // issue DMA for next slice
#pragma unroll
            for (int q = 0; q < 4; ++q) {
                int rl = (w * 4 + q) * 8 + rowInGrp;
                gload16(attnL + (size_t)(t0 + rl) * 256 + (ks + 1) * 64 + srcChunk * 8,
                        &Blds[(ks + 1) & 1][0] + (size_t)(w * 4 + q) * 512);
            }
        }
#pragma unroll
        for (int kk = 0; kk < 2; ++kk) {
            bf16x8 af[4], bfr[4];
#pragma unroll
            for (int mi = 0; mi < 4; ++mi) {
                int r = wr * 64 + mi * 16 + l15;
                af[mi] = *(const bf16x8*)(Alds + r * 256 + (ks * 8 + ((kk * 4 + l4) ^ l7)) * 8);
            }
#pragma unroll
            for (int ni = 0; ni < 4; ++ni) {
                int r = wc * 64 + ni * 16 + l15;
                bfr[ni] = *(const bf16x8*)(Bl + r * 64 + ((kk * 4 + l4) ^ l7) * 8);
            }
#pragma unroll
            for (int mi = 0; mi < 4; ++mi)
#pragma unroll
                for (int ni = 0; ni < 4; ++ni)
                    acc[mi][ni] = __builtin_amdgcn_mfma_f32_16x16x32_bf16(
                        af[mi], bfr[ni], acc[mi][ni], 0, 0, 0);
        }
        __syncthreads();                            // drains DMA + readers
    }

    const int b = t0 >> 12, sb = t0 & 4095;
#pragma unroll
    for (int mi = 0; mi < 4; ++mi) {
#pragma unroll
        for (int rg = 0; rg < 4; ++rg) {
            int o = o0 + wr * 64 + mi * 16 + l4 * 4 + rg;
            float bb = bo[o];
            float* yrow = y + ((size_t)(b * 256 + o)) * 4096 + sb + wc * 64;
#pragma unroll
            for (int ni = 0; ni < 4; ++ni)
                yrow[ni * 16 + l15] = acc[mi][ni][rg] + bb;
        }
    }
}

// ============================ launcher ======================================
extern "C" void kernel_launch(void* const* d_in, const int* in_sizes, int n_in,
                              void* d_out, int out_size, void* d_ws, size_t ws_size,
                              hipStream_t stream)
{
    const float* x   = (const float*)d_in[0];
    const float* Wq  = (const float*)d_in[1];
    const float* bq  = (const float*)d_in[2];
    const float* Wk  = (const float*)d_in[3];
    const float* bk  = (const float*)d_in[4];
    const float* Wv  = (const float*)d_in[5];
    const float* bv  = (const float*)d_in[6];
    const float* dwk = (const float*)d_in[7];
    const float* dwb = (const float*)d_in[8];
    const float* Wo  = (const float*)d_in[9];
    const float* bo  = (const float*)d_in[10];
    float* y = (float*)d_out;

    char* ws = (char*)d_ws;
    const size_t MB = 1024 * 1024;
    float2* csT = (float2*)(ws);                     // 1 MB [4096][32] (cos,sin)
    u16* WTq = (u16*)(ws + 1 * MB);                  // 4 x 128 KB (contiguous)
    u16* WTk = WTq + 65536;
    u16* WTv = WTk + 65536;
    u16* WoT = WTv + 65536;
    u16* qr   = (u16*)(ws + 2 * MB);                 // 32 MB each
    u16* kr   = (u16*)(ws + 2 * MB + 32 * MB);
    u16* v    = (u16*)(ws + 2 * MB + 64 * MB);
    u16* lepe = (u16*)(ws + 2 * MB + 96 * MB);
    u16* v5   = (u16*)(ws + 2 * MB + 128 * MB);      // (b,w,n,h,d)
    u16* attn = v;                                    // reuse (attn + lepe)

    k_init<<<dim3(768), dim3(256), 0, stream>>>(
        csT, Wq, Wk, Wv, Wo, WTq, WTk, WTv, WoT);
    k_qkv_fused<<<dim3(512), dim3(512), 0, stream>>>(
        x, WTq, bq, bk, bv, csT, qr, kr, v, v5);
    k_lepe<<<dim3(64, 4, 16), dim3(256), 0, stream>>>(v, dwk, dwb, lepe);
    k_attn_h<<<dim3(1024), dim3(256), 0, stream>>>(qr, kr, v5, lepe, attn);
    k_proj_fused<<<dim3(512), dim3(512), 0, stream>>>(WoT, attn, bo, y);
}